// Round 5
// baseline (10382.309 us; speedup 1.0000x reference)
//
#include <hip/hip_runtime.h>
#include <math.h>

// Stacked LSTM B=64, T=512, D=H=512, L=3 (gate order i,f,g,o).
// 192 persistent WGs = 3 layers x 64 colgroups (8 h-cols = 32 z-cols each).
// Split-bf16 (hi+lo) MFMA, 3-term product: z = ah*bh + ah*bl + al*bh (~2^-17 rel).
// Waves = k-quarters (w<2: input half, w>=2: recurrent half).
// Hi-weights in LDS (66KB), lo-weights persistent in VGPRs (64/wave).
//
// r5 sync redesign (r4 measured 19.8us/beat, MfmaUtil 4.8% -> sync-bound):
//  - per-WG monotonic flag words flags[l][cg] = completed step count
//    (release STORE, no RMW -> no cacheline ping-pong serialization)
//  - consumer checks 64 producers in ONE parallel load (lane i -> flag i, __all)
//  - polls moved into wave branches: waves 0-1 wait input flag, waves 2-3 wait
//    own-layer flag -> W*x half overlaps the recurrent critical chain.
// Compute core (fragment maps, LDS layouts, finalize) identical to validated r4.

#define T_ 512
#define RING_US (3 * 8 * 64 * 512)        // 786432 ushorts per ring array
#define XH_OFF_US (2 * 1024 * 1024)       // x_hi at byte offset 4MB (rings+flags < 4MB)
#define XL_OFF_US (XH_OFF_US + 16777216)  // x_lo
#define WS_NEED_XS ((size_t)(XL_OFF_US + 16777216) * 2)

typedef float f32x4 __attribute__((ext_vector_type(4)));
typedef short s16x8 __attribute__((ext_vector_type(8)));

__device__ __forceinline__ unsigned short bf16hi(float f) {
  unsigned u = __float_as_uint(f);
  u += 0x7FFFu + ((u >> 16) & 1u);  // RNE
  return (unsigned short)(u >> 16);
}
__device__ __forceinline__ float bf2f(unsigned short h) {
  return __uint_as_float(((unsigned)h) << 16);
}
__device__ __forceinline__ float sigf(float z) { return 1.f / (1.f + __expf(-z)); }
__device__ __forceinline__ float tanhf_(float z) { return 2.f * sigf(2.f * z) - 1.f; }

__device__ __forceinline__ void split8(const float* p, s16x8* hi, s16x8* lo) {
  union { s16x8 s; unsigned u[4]; } Uh, Ul;
#pragma unroll
  for (int e = 0; e < 4; ++e) {
    float f0 = p[2 * e], f1 = p[2 * e + 1];
    unsigned short h0 = bf16hi(f0), h1 = bf16hi(f1);
    unsigned short l0 = bf16hi(f0 - bf2f(h0)), l1 = bf16hi(f1 - bf2f(h1));
    Uh.u[e] = (unsigned)h0 | ((unsigned)h1 << 16);
    Ul.u[e] = (unsigned)l0 | ((unsigned)l1 << 16);
  }
  *hi = Uh.s; *lo = Ul.s;
}

__device__ __forceinline__ void do_mfma(const s16x8* ah, const s16x8* al,
                                        s16x8 bh0, s16x8 bh1, s16x8 bl0, s16x8 bl1,
                                        f32x4 acc[4][2]) {
#pragma unroll
  for (int m = 0; m < 4; ++m) {
    acc[m][0] = __builtin_amdgcn_mfma_f32_16x16x32_bf16(ah[m], bh0, acc[m][0], 0, 0, 0);
    acc[m][0] = __builtin_amdgcn_mfma_f32_16x16x32_bf16(ah[m], bl0, acc[m][0], 0, 0, 0);
    acc[m][0] = __builtin_amdgcn_mfma_f32_16x16x32_bf16(al[m], bh0, acc[m][0], 0, 0, 0);
    acc[m][1] = __builtin_amdgcn_mfma_f32_16x16x32_bf16(ah[m], bh1, acc[m][1], 0, 0, 0);
    acc[m][1] = __builtin_amdgcn_mfma_f32_16x16x32_bf16(ah[m], bl1, acc[m][1], 0, 0, 0);
    acc[m][1] = __builtin_amdgcn_mfma_f32_16x16x32_bf16(al[m], bh1, acc[m][1], 0, 0, 0);
  }
}

// spin until all 64 flags[base + lane] >= tgt (whole wave participates)
__device__ __forceinline__ void wait_flags(const unsigned int* f, int lane,
                                           unsigned int tgt) {
  while (true) {
    unsigned int v = __hip_atomic_load(&f[lane], __ATOMIC_RELAXED,
                                       __HIP_MEMORY_SCOPE_AGENT);
    if (__all((int)(v >= tgt))) break;
    __builtin_amdgcn_s_sleep(1);
  }
}

__global__ __launch_bounds__(256) void init_kernel(const float* __restrict__ x,
                                                   float* __restrict__ ws_f,
                                                   int do_x) {
  unsigned short* rh = (unsigned short*)ws_f;
  unsigned short* rl = rh + RING_US;
  unsigned int* flags = (unsigned int*)(rh + 2 * RING_US);
  const int bid = blockIdx.x, tid = threadIdx.x;
  if (bid < 2048) {
    if (!do_x) return;
    // Tile (t, 128 d-cols): fp32 -> bf16 hi/lo in fragment layout
    // x[b][t][d] -> xh/xl[((t*64 + d/8)*64 + b)*8 + d%8]
    __shared__ float tile[64 * 132];
    const int t = bid >> 2, dq = bid & 3;
#pragma unroll
    for (int i = 0; i < 32; ++i) {
      int idx = tid + i * 256;
      int b = idx >> 7, dd = idx & 127;
      tile[b * 132 + dd] = x[((size_t)b * 512 + t) * 512 + dq * 128 + dd];
    }
    __syncthreads();
    ushort4* xh4 = (ushort4*)(rh + XH_OFF_US);
    ushort4* xl4 = (ushort4*)(rh + XL_OFF_US);
#pragma unroll
    for (int i = 0; i < 8; ++i) {
      int o4 = tid + i * 256;      // 2048 ushort4 per array per tile
      int dl = o4 >> 7;            // local dchunk 0..15
      int b = (o4 >> 1) & 63;
      int c4 = (o4 & 1) * 4;
      const float* tp = tile + b * 132 + dl * 8 + c4;
      float f0 = tp[0], f1 = tp[1], f2 = tp[2], f3 = tp[3];
      unsigned short h0 = bf16hi(f0), h1 = bf16hi(f1), h2 = bf16hi(f2), h3 = bf16hi(f3);
      ushort4 vh = make_ushort4(h0, h1, h2, h3);
      ushort4 vl = make_ushort4(bf16hi(f0 - bf2f(h0)), bf16hi(f1 - bf2f(h1)),
                                bf16hi(f2 - bf2f(h2)), bf16hi(f3 - bf2f(h3)));
      int gi = t * 8192 + (dq * 16 + dl) * 128 + b * 2 + (o4 & 1);
      xh4[gi] = vh;
      xl4[gi] = vl;
    }
  } else {
    // zero ring slot 0 of each layer (h(-1) = 0) and the 192 flag words
    const int idx0 = (bid - 2048) * 256 + tid;
    for (int e = idx0; e < 3 * 32768; e += 8 * 256) {
      int l = e >> 15, off = e & 32767;
      rh[l * 262144 + off] = 0;
      rl[l * 262144 + off] = 0;
    }
    if (idx0 < 192) flags[idx0] = 0u;
  }
}

template <bool XS>
__global__ __launch_bounds__(256) void lstm_kernel(const float* __restrict__ W,
                                                   const float* __restrict__ U,
                                                   const float* __restrict__ bia,
                                                   const float* __restrict__ x,
                                                   float* __restrict__ ws_f,
                                                   float* __restrict__ out) {
  __shared__ unsigned short smWh[32 * 1032];  // hi-weights, [col][k] pad-chunked
  __shared__ float pbuf[8192];                // lo-stage / k-partial exchange

  const int tid = threadIdx.x;
  const int l = blockIdx.x >> 6;
  const int cg = blockIdx.x & 63;
  const int w = tid >> 6;                    // wave = k-quarter; Mtile at finalize
  const int lane = tid & 63;
  const int cl = lane & 15, kg = lane >> 4;  // fragment col/row-group
  const int j = lane & 7, rp = lane >> 3;    // finalize: hcol j, row-pair rp

  unsigned short* rh = (unsigned short*)ws_f;
  unsigned short* rl = rh + RING_US;
  unsigned int* flags = (unsigned int*)(rh + 2 * RING_US);

  // ---- stage hi-weights (all k) to LDS; lo-weights to VGPRs in 2 passes ----
  {
    unsigned short* plo = (unsigned short*)pbuf;
    const int c = tid & 31, ks0 = tid >> 5;
    const int gcol = (c >> 3) * 512 + cg * 8 + (c & 7);
    for (int k = ks0; k < 1024; k += 8) {
      float f = (k < 512) ? W[((size_t)l * 512 + k) * 2048 + gcol]
                          : U[((size_t)l * 512 + (k - 512)) * 2048 + gcol];
      unsigned short h = bf16hi(f);
      smWh[c * 1032 + (k >> 3) * 8 + (k & 7)] = h;
      if (k < 512) plo[c * 512 + k] = bf16hi(f - bf2f(h));
    }
  }
  __syncthreads();
  s16x8 wl[2][8];  // persistent lo-weight fragments, this wave's k-quarter
  if (w < 2) {
#pragma unroll
    for (int nt = 0; nt < 2; ++nt)
#pragma unroll
      for (int ks = 0; ks < 8; ++ks)
        wl[nt][ks] = *(const s16x8*)((const unsigned short*)pbuf +
                       (nt * 16 + cl) * 512 + w * 256 + ks * 32 + kg * 8);
  }
  __syncthreads();
  {
    unsigned short* plo = (unsigned short*)pbuf;
    const int c = tid & 31, ks0 = tid >> 5;
    const int gcol = (c >> 3) * 512 + cg * 8 + (c & 7);
    for (int k = 512 + ks0; k < 1024; k += 8) {
      float f = U[((size_t)l * 512 + (k - 512)) * 2048 + gcol];
      unsigned short h = bf16hi(f);
      plo[c * 512 + (k - 512)] = bf16hi(f - bf2f(h));
    }
  }
  __syncthreads();
  if (w >= 2) {
#pragma unroll
    for (int nt = 0; nt < 2; ++nt)
#pragma unroll
      for (int ks = 0; ks < 8; ++ks)
        wl[nt][ks] = *(const s16x8*)((const unsigned short*)pbuf +
                       (nt * 16 + cl) * 512 + (w - 2) * 256 + ks * 32 + kg * 8);
  }
  __syncthreads();

  const float bias_g[4] = {bia[l * 2048 + 0 * 512 + cg * 8 + j],
                           bia[l * 2048 + 1 * 512 + cg * 8 + j],
                           bia[l * 2048 + 2 * 512 + cg * 8 + j],
                           bia[l * 2048 + 3 * 512 + cg * 8 + j]};
  float c_st0 = 0.f, c_st1 = 0.f;  // cell state rows w*16+rp*2(+1), hcol cg*8+j

  const int whb0 = cl * 1032 + w * 256 + kg * 8;         // Nt0 hi-weight base
  const int whb1 = (16 + cl) * 1032 + w * 256 + kg * 8;  // Nt1

  for (int t = 0; t < T_; ++t) {
    const int slot = (t + 1) & 7, pslot = t & 7;
    f32x4 acc[4][2];
#pragma unroll
    for (int m = 0; m < 4; ++m) { acc[m][0] = (f32x4)(0.f); acc[m][1] = (f32x4)(0.f); }

    if (w < 2) {
      // ---------- input half: depends only on h(l-1,t) / x(t) ----------
      if (l > 0) {
        wait_flags(flags + (l - 1) * 64, lane, (unsigned)(t + 1));
        __builtin_amdgcn_fence(__ATOMIC_ACQUIRE, "agent");
      }
      if (!XS && l == 0) {
        // fallback: fp32 x, split in-register
        for (int ks = 0; ks < 8; ++ks) {
          s16x8 ah[4], al[4];
#pragma unroll
          for (int m = 0; m < 4; ++m)
            split8(x + ((size_t)(m * 16 + cl) * 512 + t) * 512 + w * 256 + ks * 32 + kg * 8,
                   &ah[m], &al[m]);
          s16x8 bh0 = *(const s16x8*)(smWh + whb0 + ks * 32);
          s16x8 bh1 = *(const s16x8*)(smWh + whb1 + ks * 32);
          do_mfma(ah, al, bh0, bh1, wl[0][ks], wl[1][ks], acc);
        }
      } else {
        const unsigned short *pah, *pal;
        if (XS && l == 0) {
          pah = rh + XH_OFF_US + t * 32768;
          pal = rh + XL_OFF_US + t * 32768;
        } else {
          pah = rh + ((l - 1) * 8 + slot) * 32768;  // h(l-1, t)
          pal = rl + ((l - 1) * 8 + slot) * 32768;
        }
        const int cb = w * 32;
        for (int ks = 0; ks < 8; ++ks) {
          s16x8 ah[4], al[4];
#pragma unroll
          for (int m = 0; m < 4; ++m) {
            int off = (cb + ks * 4 + kg) * 512 + (m * 16 + cl) * 8;
            ah[m] = *(const s16x8*)(pah + off);
            al[m] = *(const s16x8*)(pal + off);
          }
          s16x8 bh0 = *(const s16x8*)(smWh + whb0 + ks * 32);
          s16x8 bh1 = *(const s16x8*)(smWh + whb1 + ks * 32);
          do_mfma(ah, al, bh0, bh1, wl[0][ks], wl[1][ks], acc);
        }
      }
    } else {
      // ---------- recurrent half: the critical chain ----------
      wait_flags(flags + l * 64, lane, (unsigned)t);  // own h(t-1) complete
      if (l < 2 && t >= 8)                            // ring slot reuse guard
        wait_flags(flags + (l + 1) * 64, lane, (unsigned)(t - 7));
      __builtin_amdgcn_fence(__ATOMIC_ACQUIRE, "agent");
      const unsigned short* pah = rh + (l * 8 + pslot) * 32768;  // h(l, t-1)
      const unsigned short* pal = rl + (l * 8 + pslot) * 32768;
      const int cb = (w - 2) * 32;
      for (int ks = 0; ks < 8; ++ks) {
        s16x8 ah[4], al[4];
#pragma unroll
        for (int m = 0; m < 4; ++m) {
          int off = (cb + ks * 4 + kg) * 512 + (m * 16 + cl) * 8;
          ah[m] = *(const s16x8*)(pah + off);
          al[m] = *(const s16x8*)(pal + off);
        }
        s16x8 bh0 = *(const s16x8*)(smWh + whb0 + ks * 32);
        s16x8 bh1 = *(const s16x8*)(smWh + whb1 + ks * 32);
        do_mfma(ah, al, bh0, bh1, wl[0][ks], wl[1][ks], acc);
      }
    }

    // ---- k-partials to LDS (C/D layout: col=lane&15, row=(lane>>4)*4+reg) ----
#pragma unroll
    for (int m = 0; m < 4; ++m)
#pragma unroll
      for (int n = 0; n < 2; ++n)
        *(f32x4*)(pbuf + (((w * 4 + m) * 2 + n) * 16 + cl) * 16 + kg * 4) = acc[m][n];
    __syncthreads();

    // ---- finalize: wave w = Mtile, lane (j,rp) = hcol j, rows rp*2, rp*2+1 ----
    float z0[4], z1[4];
#pragma unroll
    for (int g = 0; g < 4; ++g) {
      int nt = g >> 1, cc = (g & 1) * 8 + j;
      float a0 = 0.f, a1 = 0.f;
#pragma unroll
      for (int sw = 0; sw < 4; ++sw) {
        float2 v = *(const float2*)(pbuf + (((sw * 4 + w) * 2 + nt) * 16 + cc) * 16 +
                                    (rp >> 1) * 4 + (rp & 1) * 2);
        a0 += v.x; a1 += v.y;
      }
      z0[g] = a0 + bias_g[g]; z1[g] = a1 + bias_g[g];
    }
    float iv0 = sigf(z0[0]), fv0 = sigf(z0[1]), gv0 = tanhf_(z0[2]), ov0 = sigf(z0[3]);
    float iv1 = sigf(z1[0]), fv1 = sigf(z1[1]), gv1 = tanhf_(z1[2]), ov1 = sigf(z1[3]);
    c_st0 = fv0 * c_st0 + iv0 * gv0;
    c_st1 = fv1 * c_st1 + iv1 * gv1;
    float h0 = ov0 * tanhf_(c_st0);
    float h1 = ov1 * tanhf_(c_st1);

    const int grow0 = w * 16 + rp * 2, grow1 = grow0 + 1;
    unsigned short hh0 = bf16hi(h0), hh1 = bf16hi(h1);
    unsigned short hl0 = bf16hi(h0 - bf2f(hh0)), hl1 = bf16hi(h1 - bf2f(hh1));
    size_t wb = (size_t)(l * 8 + slot) * 32768 + cg * 512;
    rh[wb + grow0 * 8 + j] = hh0;
    rl[wb + grow0 * 8 + j] = hl0;
    rh[wb + grow1 * 8 + j] = hh1;
    rl[wb + grow1 * 8 + j] = hl1;
    if (l == 2 && t == T_ - 1) {
      out[grow0 * 512 + cg * 8 + j] = h0;
      out[grow1 * 512 + cg * 8 + j] = h1;
    }
    __syncthreads();  // drains all waves' ring stores (vmcnt); protects pbuf WAR

    if (tid == 0) {
      // release STORE: prior writes (whole WG, drained by the barrier) become
      // agent-visible before the flag value; no RMW -> no line serialization
      __hip_atomic_store(&flags[l * 64 + cg], (unsigned)(t + 1), __ATOMIC_RELEASE,
                         __HIP_MEMORY_SCOPE_AGENT);
    }
  }
}

extern "C" void kernel_launch(void* const* d_in, const int* in_sizes, int n_in,
                              void* d_out, int out_size, void* d_ws, size_t ws_size,
                              hipStream_t stream) {
  (void)in_sizes; (void)n_in; (void)out_size;
  const float* x = (const float*)d_in[0];
  const float* W = (const float*)d_in[1];
  const float* U = (const float*)d_in[2];
  const float* b = (const float*)d_in[3];
  float* out = (float*)d_out;
  float* ws = (float*)d_ws;
  const int xs = (ws_size >= WS_NEED_XS) ? 1 : 0;

  hipLaunchKernelGGL(init_kernel, dim3(2056), dim3(256), 0, stream, x, ws, xs);
  if (xs)
    hipLaunchKernelGGL((lstm_kernel<true>), dim3(192), dim3(256), 0, stream,
                       W, U, b, x, ws, out);
  else
    hipLaunchKernelGGL((lstm_kernel<false>), dim3(192), dim3(256), 0, stream,
                       W, U, b, x, ws, out);
}

// Round 6
// 8126.694 us; speedup vs baseline: 1.2776x; 1.2776x over previous
//
#include <hip/hip_runtime.h>
#include <math.h>

// Stacked LSTM B=64, T=512, D=H=512, L=3 (gate order i,f,g,o).
// 192 persistent WGs = 3 layers x 64 colgroups (8 h-cols = 32 z-cols each).
// Split-bf16 (hi+lo) MFMA, 3-term product: z = ah*bh + ah*bl + al*bh (~2^-17 rel).
// Waves = k-quarters (w<2: input half, w>=2: recurrent half).
// Hi-weights in LDS (66KB), lo-weights persistent in VGPRs (64/wave).
//
// r6: kill per-step L2 maintenance (r4/r5 both ~20us/beat, MfmaUtil 4.8%,
// unchanged by sync redesign -> fences, not flag mechanics, are the cost).
//  - ring stores:  global_store_short  sc0 sc1  (write-through L2 -> L3)
//  - ring loads:   global_load_dwordx4 sc0 sc1  (bypass L1+L2, read L3)
//  - NO acquire/release fences anywhere in the loop; flag store stays a
//    RELEASE agent atomic (its wbl2 is ~empty now), polls stay relaxed agent
//    atomics (proven L3-direct by r4/r5 passing).
//  - x / weights stay plain cached loads (read-only, no coherence hazard).
//  - loads issued 8-per-ks then one vmcnt(0)+sched_barrier (rule: compiler
//    won't auto-wait inline-asm loads; MFMA must not hoist past the wait).
//  - ring-reuse guard poll moved to waves 0-1 (off recurrent critical path).

#define T_ 512
#define RING_US (3 * 8 * 64 * 512)        // 786432 ushorts per ring array
#define XH_OFF_US (2 * 1024 * 1024)       // x_hi at byte offset 4MB
#define XL_OFF_US (XH_OFF_US + 16777216)  // x_lo
#define WS_NEED_XS ((size_t)(XL_OFF_US + 16777216) * 2)

typedef float f32x4 __attribute__((ext_vector_type(4)));
typedef short s16x8 __attribute__((ext_vector_type(8)));
typedef int i32x4 __attribute__((ext_vector_type(4)));

__device__ __forceinline__ unsigned short bf16hi(float f) {
  unsigned u = __float_as_uint(f);
  u += 0x7FFFu + ((u >> 16) & 1u);  // RNE
  return (unsigned short)(u >> 16);
}
__device__ __forceinline__ float bf2f(unsigned short h) {
  return __uint_as_float(((unsigned)h) << 16);
}
__device__ __forceinline__ float sigf(float z) { return 1.f / (1.f + __expf(-z)); }
__device__ __forceinline__ float tanhf_(float z) { return 2.f * sigf(2.f * z) - 1.f; }

// Issue an L1+L2-bypassing 16B load (served by L3 coherence point). NO wait:
// caller must s_waitcnt vmcnt(0) + sched_barrier(0) before consuming.
__device__ __forceinline__ void ld_sys(i32x4* d, const void* p) {
  asm volatile("global_load_dwordx4 %0, %1, off sc0 sc1" : "=v"(*d) : "v"(p));
}
// Write-through 2-byte store (reaches L3 before vmcnt retires).
__device__ __forceinline__ void st_sys_u16(unsigned short* p, unsigned v) {
  asm volatile("global_store_short %0, %1, off sc0 sc1" :: "v"(p), "v"(v) : "memory");
}

__device__ __forceinline__ void split8(const float* p, s16x8* hi, s16x8* lo) {
  union { s16x8 s; unsigned u[4]; } Uh, Ul;
#pragma unroll
  for (int e = 0; e < 4; ++e) {
    float f0 = p[2 * e], f1 = p[2 * e + 1];
    unsigned short h0 = bf16hi(f0), h1 = bf16hi(f1);
    unsigned short l0 = bf16hi(f0 - bf2f(h0)), l1 = bf16hi(f1 - bf2f(h1));
    Uh.u[e] = (unsigned)h0 | ((unsigned)h1 << 16);
    Ul.u[e] = (unsigned)l0 | ((unsigned)l1 << 16);
  }
  *hi = Uh.s; *lo = Ul.s;
}

__device__ __forceinline__ void do_mfma(const s16x8* ah, const s16x8* al,
                                        s16x8 bh0, s16x8 bh1, s16x8 bl0, s16x8 bl1,
                                        f32x4 acc[4][2]) {
#pragma unroll
  for (int m = 0; m < 4; ++m) {
    acc[m][0] = __builtin_amdgcn_mfma_f32_16x16x32_bf16(ah[m], bh0, acc[m][0], 0, 0, 0);
    acc[m][0] = __builtin_amdgcn_mfma_f32_16x16x32_bf16(ah[m], bl0, acc[m][0], 0, 0, 0);
    acc[m][0] = __builtin_amdgcn_mfma_f32_16x16x32_bf16(al[m], bh0, acc[m][0], 0, 0, 0);
    acc[m][1] = __builtin_amdgcn_mfma_f32_16x16x32_bf16(ah[m], bh1, acc[m][1], 0, 0, 0);
    acc[m][1] = __builtin_amdgcn_mfma_f32_16x16x32_bf16(ah[m], bl1, acc[m][1], 0, 0, 0);
    acc[m][1] = __builtin_amdgcn_mfma_f32_16x16x32_bf16(al[m], bh1, acc[m][1], 0, 0, 0);
  }
}

// spin until all 64 flags[base + lane] >= tgt (whole wave participates)
__device__ __forceinline__ void wait_flags(const unsigned int* f, int lane,
                                           unsigned int tgt) {
  while (true) {
    unsigned int v = __hip_atomic_load(&f[lane], __ATOMIC_RELAXED,
                                       __HIP_MEMORY_SCOPE_AGENT);
    if (__all((int)(v >= tgt))) break;
    __builtin_amdgcn_s_sleep(1);
  }
}

__global__ __launch_bounds__(256) void init_kernel(const float* __restrict__ x,
                                                   float* __restrict__ ws_f,
                                                   int do_x) {
  unsigned short* rh = (unsigned short*)ws_f;
  unsigned short* rl = rh + RING_US;
  unsigned int* flags = (unsigned int*)(rh + 2 * RING_US);
  const int bid = blockIdx.x, tid = threadIdx.x;
  if (bid < 2048) {
    if (!do_x) return;
    // Tile (t, 128 d-cols): fp32 -> bf16 hi/lo in fragment layout
    // x[b][t][d] -> xh/xl[((t*64 + d/8)*64 + b)*8 + d%8]
    __shared__ float tile[64 * 132];
    const int t = bid >> 2, dq = bid & 3;
#pragma unroll
    for (int i = 0; i < 32; ++i) {
      int idx = tid + i * 256;
      int b = idx >> 7, dd = idx & 127;
      tile[b * 132 + dd] = x[((size_t)b * 512 + t) * 512 + dq * 128 + dd];
    }
    __syncthreads();
    ushort4* xh4 = (ushort4*)(rh + XH_OFF_US);
    ushort4* xl4 = (ushort4*)(rh + XL_OFF_US);
#pragma unroll
    for (int i = 0; i < 8; ++i) {
      int o4 = tid + i * 256;      // 2048 ushort4 per array per tile
      int dl = o4 >> 7;            // local dchunk 0..15
      int b = (o4 >> 1) & 63;
      int c4 = (o4 & 1) * 4;
      const float* tp = tile + b * 132 + dl * 8 + c4;
      float f0 = tp[0], f1 = tp[1], f2 = tp[2], f3 = tp[3];
      unsigned short h0 = bf16hi(f0), h1 = bf16hi(f1), h2 = bf16hi(f2), h3 = bf16hi(f3);
      ushort4 vh = make_ushort4(h0, h1, h2, h3);
      ushort4 vl = make_ushort4(bf16hi(f0 - bf2f(h0)), bf16hi(f1 - bf2f(h1)),
                                bf16hi(f2 - bf2f(h2)), bf16hi(f3 - bf2f(h3)));
      int gi = t * 8192 + (dq * 16 + dl) * 128 + b * 2 + (o4 & 1);
      xh4[gi] = vh;
      xl4[gi] = vl;
    }
  } else {
    // zero ring slot 0 of each layer (h(-1) = 0) and the 192 flag words.
    // (dispatch-end system flush makes these L3-visible to the lstm kernel)
    const int idx0 = (bid - 2048) * 256 + tid;
    for (int e = idx0; e < 3 * 32768; e += 8 * 256) {
      int l = e >> 15, off = e & 32767;
      rh[l * 262144 + off] = 0;
      rl[l * 262144 + off] = 0;
    }
    if (idx0 < 192) flags[idx0] = 0u;
  }
}

template <bool XS>
__global__ __launch_bounds__(256) void lstm_kernel(const float* __restrict__ W,
                                                   const float* __restrict__ U,
                                                   const float* __restrict__ bia,
                                                   const float* __restrict__ x,
                                                   float* __restrict__ ws_f,
                                                   float* __restrict__ out) {
  __shared__ unsigned short smWh[32 * 1032];  // hi-weights, [col][k] pad-chunked
  __shared__ float pbuf[8192];                // lo-stage / k-partial exchange

  const int tid = threadIdx.x;
  const int l = blockIdx.x >> 6;
  const int cg = blockIdx.x & 63;
  const int w = tid >> 6;                    // wave = k-quarter; Mtile at finalize
  const int lane = tid & 63;
  const int cl = lane & 15, kg = lane >> 4;  // fragment col/row-group
  const int j = lane & 7, rp = lane >> 3;    // finalize: hcol j, row-pair rp

  unsigned short* rh = (unsigned short*)ws_f;
  unsigned short* rl = rh + RING_US;
  unsigned int* flags = (unsigned int*)(rh + 2 * RING_US);

  // ---- stage hi-weights (all k) to LDS; lo-weights to VGPRs in 2 passes ----
  {
    unsigned short* plo = (unsigned short*)pbuf;
    const int c = tid & 31, ks0 = tid >> 5;
    const int gcol = (c >> 3) * 512 + cg * 8 + (c & 7);
    for (int k = ks0; k < 1024; k += 8) {
      float f = (k < 512) ? W[((size_t)l * 512 + k) * 2048 + gcol]
                          : U[((size_t)l * 512 + (k - 512)) * 2048 + gcol];
      unsigned short h = bf16hi(f);
      smWh[c * 1032 + (k >> 3) * 8 + (k & 7)] = h;
      if (k < 512) plo[c * 512 + k] = bf16hi(f - bf2f(h));
    }
  }
  __syncthreads();
  s16x8 wl[2][8];  // persistent lo-weight fragments, this wave's k-quarter
  if (w < 2) {
#pragma unroll
    for (int nt = 0; nt < 2; ++nt)
#pragma unroll
      for (int ks = 0; ks < 8; ++ks)
        wl[nt][ks] = *(const s16x8*)((const unsigned short*)pbuf +
                       (nt * 16 + cl) * 512 + w * 256 + ks * 32 + kg * 8);
  }
  __syncthreads();
  {
    unsigned short* plo = (unsigned short*)pbuf;
    const int c = tid & 31, ks0 = tid >> 5;
    const int gcol = (c >> 3) * 512 + cg * 8 + (c & 7);
    for (int k = 512 + ks0; k < 1024; k += 8) {
      float f = U[((size_t)l * 512 + (k - 512)) * 2048 + gcol];
      unsigned short h = bf16hi(f);
      plo[c * 512 + (k - 512)] = bf16hi(f - bf2f(h));
    }
  }
  __syncthreads();
  if (w >= 2) {
#pragma unroll
    for (int nt = 0; nt < 2; ++nt)
#pragma unroll
      for (int ks = 0; ks < 8; ++ks)
        wl[nt][ks] = *(const s16x8*)((const unsigned short*)pbuf +
                       (nt * 16 + cl) * 512 + (w - 2) * 256 + ks * 32 + kg * 8);
  }
  __syncthreads();

  const float bias_g[4] = {bia[l * 2048 + 0 * 512 + cg * 8 + j],
                           bia[l * 2048 + 1 * 512 + cg * 8 + j],
                           bia[l * 2048 + 2 * 512 + cg * 8 + j],
                           bia[l * 2048 + 3 * 512 + cg * 8 + j]};
  float c_st0 = 0.f, c_st1 = 0.f;  // cell state rows w*16+rp*2(+1), hcol cg*8+j

  const int whb0 = cl * 1032 + w * 256 + kg * 8;         // Nt0 hi-weight base
  const int whb1 = (16 + cl) * 1032 + w * 256 + kg * 8;  // Nt1

  for (int t = 0; t < T_; ++t) {
    const int slot = (t + 1) & 7, pslot = t & 7;
    f32x4 acc[4][2];
#pragma unroll
    for (int m = 0; m < 4; ++m) { acc[m][0] = (f32x4)(0.f); acc[m][1] = (f32x4)(0.f); }

    if (w < 2) {
      // ---------- input half: depends on h(l-1,t) / x(t); also carries the
      // ring-reuse guard (off the recurrent critical path) ----------
      if (l > 0) wait_flags(flags + (l - 1) * 64, lane, (unsigned)(t + 1));
      if (l < 2 && t >= 8) wait_flags(flags + (l + 1) * 64, lane, (unsigned)(t - 7));
      if (!XS && l == 0) {
        // fallback: fp32 x, split in-register (plain cached loads)
        for (int ks = 0; ks < 8; ++ks) {
          s16x8 ah[4], al[4];
#pragma unroll
          for (int m = 0; m < 4; ++m)
            split8(x + ((size_t)(m * 16 + cl) * 512 + t) * 512 + w * 256 + ks * 32 + kg * 8,
                   &ah[m], &al[m]);
          s16x8 bh0 = *(const s16x8*)(smWh + whb0 + ks * 32);
          s16x8 bh1 = *(const s16x8*)(smWh + whb1 + ks * 32);
          do_mfma(ah, al, bh0, bh1, wl[0][ks], wl[1][ks], acc);
        }
      } else if (XS && l == 0) {
        // x pre-split: read-only -> plain cached loads (L2 reuse, no hazard)
        const unsigned short* pah = rh + XH_OFF_US + t * 32768;
        const unsigned short* pal = rh + XL_OFF_US + t * 32768;
        const int cb = w * 32;
        for (int ks = 0; ks < 8; ++ks) {
          s16x8 ah[4], al[4];
#pragma unroll
          for (int m = 0; m < 4; ++m) {
            int off = (cb + ks * 4 + kg) * 512 + (m * 16 + cl) * 8;
            ah[m] = *(const s16x8*)(pah + off);
            al[m] = *(const s16x8*)(pal + off);
          }
          s16x8 bh0 = *(const s16x8*)(smWh + whb0 + ks * 32);
          s16x8 bh1 = *(const s16x8*)(smWh + whb1 + ks * 32);
          do_mfma(ah, al, bh0, bh1, wl[0][ks], wl[1][ks], acc);
        }
      } else {
        // h(l-1, t) from ring: L2-bypass loads (L3 is the coherence point)
        const unsigned short* pah = rh + ((l - 1) * 8 + slot) * 32768;
        const unsigned short* pal = rl + ((l - 1) * 8 + slot) * 32768;
        const int cb = w * 32;
        for (int ks = 0; ks < 8; ++ks) {
          i32x4 vh[4], vl_[4];
#pragma unroll
          for (int m = 0; m < 4; ++m) {
            int off = (cb + ks * 4 + kg) * 512 + (m * 16 + cl) * 8;
            ld_sys(&vh[m], pah + off);
            ld_sys(&vl_[m], pal + off);
          }
          asm volatile("s_waitcnt vmcnt(0)" ::: "memory");
          __builtin_amdgcn_sched_barrier(0);
          s16x8 ah[4], al[4];
#pragma unroll
          for (int m = 0; m < 4; ++m) {
            ah[m] = __builtin_bit_cast(s16x8, vh[m]);
            al[m] = __builtin_bit_cast(s16x8, vl_[m]);
          }
          s16x8 bh0 = *(const s16x8*)(smWh + whb0 + ks * 32);
          s16x8 bh1 = *(const s16x8*)(smWh + whb1 + ks * 32);
          do_mfma(ah, al, bh0, bh1, wl[0][ks], wl[1][ks], acc);
        }
      }
    } else {
      // ---------- recurrent half: the critical chain ----------
      wait_flags(flags + l * 64, lane, (unsigned)t);  // own h(t-1) complete
      const unsigned short* pah = rh + (l * 8 + pslot) * 32768;  // h(l, t-1)
      const unsigned short* pal = rl + (l * 8 + pslot) * 32768;
      const int cb = (w - 2) * 32;
      for (int ks = 0; ks < 8; ++ks) {
        i32x4 vh[4], vl_[4];
#pragma unroll
        for (int m = 0; m < 4; ++m) {
          int off = (cb + ks * 4 + kg) * 512 + (m * 16 + cl) * 8;
          ld_sys(&vh[m], pah + off);
          ld_sys(&vl_[m], pal + off);
        }
        asm volatile("s_waitcnt vmcnt(0)" ::: "memory");
        __builtin_amdgcn_sched_barrier(0);
        s16x8 ah[4], al[4];
#pragma unroll
        for (int m = 0; m < 4; ++m) {
          ah[m] = __builtin_bit_cast(s16x8, vh[m]);
          al[m] = __builtin_bit_cast(s16x8, vl_[m]);
        }
        s16x8 bh0 = *(const s16x8*)(smWh + whb0 + ks * 32);
        s16x8 bh1 = *(const s16x8*)(smWh + whb1 + ks * 32);
        do_mfma(ah, al, bh0, bh1, wl[0][ks], wl[1][ks], acc);
      }
    }

    // ---- k-partials to LDS (C/D layout: col=lane&15, row=(lane>>4)*4+reg) ----
#pragma unroll
    for (int m = 0; m < 4; ++m)
#pragma unroll
      for (int n = 0; n < 2; ++n)
        *(f32x4*)(pbuf + (((w * 4 + m) * 2 + n) * 16 + cl) * 16 + kg * 4) = acc[m][n];
    __syncthreads();

    // ---- finalize: wave w = Mtile, lane (j,rp) = hcol j, rows rp*2, rp*2+1 ----
    float z0[4], z1[4];
#pragma unroll
    for (int g = 0; g < 4; ++g) {
      int nt = g >> 1, cc = (g & 1) * 8 + j;
      float a0 = 0.f, a1 = 0.f;
#pragma unroll
      for (int sw = 0; sw < 4; ++sw) {
        float2 v = *(const float2*)(pbuf + (((sw * 4 + w) * 2 + nt) * 16 + cc) * 16 +
                                    (rp >> 1) * 4 + (rp & 1) * 2);
        a0 += v.x; a1 += v.y;
      }
      z0[g] = a0 + bias_g[g]; z1[g] = a1 + bias_g[g];
    }
    float iv0 = sigf(z0[0]), fv0 = sigf(z0[1]), gv0 = tanhf_(z0[2]), ov0 = sigf(z0[3]);
    float iv1 = sigf(z1[0]), fv1 = sigf(z1[1]), gv1 = tanhf_(z1[2]), ov1 = sigf(z1[3]);
    c_st0 = fv0 * c_st0 + iv0 * gv0;
    c_st1 = fv1 * c_st1 + iv1 * gv1;
    float h0 = ov0 * tanhf_(c_st0);
    float h1 = ov1 * tanhf_(c_st1);

    const int grow0 = w * 16 + rp * 2, grow1 = grow0 + 1;
    unsigned short hh0 = bf16hi(h0), hh1 = bf16hi(h1);
    unsigned short hl0 = bf16hi(h0 - bf2f(hh0)), hl1 = bf16hi(h1 - bf2f(hh1));
    size_t wb = (size_t)(l * 8 + slot) * 32768 + cg * 512;
    st_sys_u16(rh + wb + grow0 * 8 + j, hh0);  // write-through -> L3
    st_sys_u16(rl + wb + grow0 * 8 + j, hl0);
    st_sys_u16(rh + wb + grow1 * 8 + j, hh1);
    st_sys_u16(rl + wb + grow1 * 8 + j, hl1);
    if (l == 2 && t == T_ - 1) {
      out[grow0 * 512 + cg * 8 + j] = h0;
      out[grow1 * 512 + cg * 8 + j] = h1;
    }
    __syncthreads();  // drains vmcnt (incl. sc1 stores); protects pbuf WAR

    if (tid == 0) {
      // RELEASE agent store: wbl2 (near-empty: ring was written-through) +
      // flag store to L3; pollers are L3-direct atomics.
      __hip_atomic_store(&flags[l * 64 + cg], (unsigned)(t + 1), __ATOMIC_RELEASE,
                         __HIP_MEMORY_SCOPE_AGENT);
    }
  }
}

extern "C" void kernel_launch(void* const* d_in, const int* in_sizes, int n_in,
                              void* d_out, int out_size, void* d_ws, size_t ws_size,
                              hipStream_t stream) {
  (void)in_sizes; (void)n_in; (void)out_size;
  const float* x = (const float*)d_in[0];
  const float* W = (const float*)d_in[1];
  const float* U = (const float*)d_in[2];
  const float* b = (const float*)d_in[3];
  float* out = (float*)d_out;
  float* ws = (float*)d_ws;
  const int xs = (ws_size >= WS_NEED_XS) ? 1 : 0;

  hipLaunchKernelGGL(init_kernel, dim3(2056), dim3(256), 0, stream, x, ws, xs);
  if (xs)
    hipLaunchKernelGGL((lstm_kernel<true>), dim3(192), dim3(256), 0, stream,
                       W, U, b, x, ws, out);
  else
    hipLaunchKernelGGL((lstm_kernel<false>), dim3(192), dim3(256), 0, stream,
                       W, U, b, x, ws, out);
}